// Round 23
// baseline (231.678 us; speedup 1.0000x reference)
//
#include <hip/hip_runtime.h>
#include <math.h>

#define T_LEN 4096
#define NBINS 2049          // T/2+1
#define B_SZ 64
#define C_IN 12
#define KM 4
#define FEAT 64

typedef __attribute__((ext_vector_type(8))) short short8v;   // 8 bf16 (4 VGPRs)
typedef __attribute__((ext_vector_type(4))) float floatx4;

// fp32 -> bf16 with RNE
__device__ __forceinline__ unsigned short f2bf(float f)
{
    unsigned int u = __float_as_uint(f);
    u += 0x7FFFu + ((u >> 16) & 1u);
    return (unsigned short)(u >> 16);
}

// FFT LDS swizzle (complex-index involution)
__device__ __forceinline__ int fphys(int i) { return i ^ ((i >> 4) & 15); }

// ---------------------------------------------------------------------------
// prep_all: twiddles (4096), gains (2049), feats-zero, 3 weight repacks.
// ---------------------------------------------------------------------------
__global__ void prep_all(const float* __restrict__ alpha,
                         const float* __restrict__ tau,
                         const float* __restrict__ omega,
                         const float* __restrict__ W1,
                         const float* __restrict__ W2,
                         const float* __restrict__ W3,
                         float2* __restrict__ tw4,
                         float* __restrict__ g,
                         float* __restrict__ feats,
                         unsigned short* __restrict__ Wp1,
                         unsigned short* __restrict__ Wp2,
                         unsigned short* __restrict__ Wp3)
{
    int gid = blockIdx.x * 256 + threadIdx.x;
    if (gid < 4096) {
        float ang = -(float)M_PI * (float)gid / 2048.0f;
        float sn, cs;
        sincosf(ang, &sn, &cs);
        tw4[gid] = make_float2(cs, sn);
        return;
    }
    gid -= 4096;
    if (gid < NBINS) {
        int f = gid;
        float freq = 0.5f * (float)f / 2048.0f;
        float a[4] = {0.f, 0.f, 0.f, 0.f};
        float s = 0.f, lamc = 0.f;
        for (int l = 0; l < 8; ++l) {
            for (int k = 0; k < 4; ++k) {
                float r = 1.f - (s - a[k]) + 0.5f * lamc;
                float d = freq - omega[k];
                float denom = 1.f + alpha[l * 4 + k] * d * d;
                float anew = r / denom;
                s += anew - a[k];
                a[k] = anew;
            }
            lamc += tau[l] * (1.f - s);
        }
        for (int k = 0; k < 4; ++k) g[k * NBINS + f] = a[k];
        return;
    }
    gid -= NBINS;
    if (gid < B_SZ * KM * FEAT) { feats[gid] = 0.f; return; }
    gid -= B_SZ * KM * FEAT;
    if (gid < KM * 4 * 32 * 32) {
        int i = gid;
        int kidx  = i & 31;
        int o     = (i >> 5) & 31;
        int dpair = (i >> 10) & 3;
        int k     = i >> 12;
        int d = dpair * 2 + (kidx >> 4);
        int c = kidx & 15;
        float v = (d < 7 && c < 12) ? W1[(((size_t)k * 32 + o) * 12 + c) * 7 + d] : 0.f;
        Wp1[(size_t)k * 4096 + dpair * 1024 + o * 32 + kidx] = f2bf(v);
        return;
    }
    gid -= KM * 4 * 32 * 32;
    if (gid < KM * 5 * 64 * 32) {
        int i = gid;
        int c = i & 31;
        int o = (i >> 5) & 63;
        int kd = i >> 11;
        int d = kd % 5, k = kd / 5;
        float v = W2[(((size_t)k * 64 + o) * 32 + c) * 5 + d];
        int sr = o >> 1;
        int q = (o & 1) * 4 + (c >> 3);
        int qp = q ^ (sr & 7);
        Wp2[(size_t)(k * 5 + d) * 2048 + sr * 64 + qp * 8 + (c & 7)] = f2bf(v);
        return;
    }
    gid -= KM * 5 * 64 * 32;
    if (gid < KM * 3 * 64 * 64) {
        int i = gid;
        int c = i & 63;
        int o = (i >> 6) & 63;
        int kd = i >> 12;
        int d = kd % 3, k = kd / 3;
        float v = W3[(((size_t)k * 64 + o) * 64 + c) * 3 + d];
        int blk = (c >> 3) ^ (o & 7);
        Wp3[(size_t)k * (3 * 64 * 64) + (d * 64 + o) * 64 + blk * 8 + (c & 7)] = f2bf(v);
        return;
    }
}

// ---------------------------------------------------------------------------
// Radix-4 Stockham, N=4096, 6 stages, swizzled LDS (verified r16).
// ---------------------------------------------------------------------------
__device__ inline float2* fft_stages4(float2* bufA, float2* bufB,
                                      const float2* __restrict__ tw4, float syf)
{
    float2* src = bufA;
    float2* dst = bufB;
#pragma unroll
    for (int st = 0; st < 6; ++st) {
        const int sh = 2 * st;
        const int s = 1 << sh;
        for (int v = threadIdx.x; v < 1024; v += 512) {
            const int q = v & (s - 1);
            const int p = v >> sh;
            float2 a = src[fphys(v)];
            float2 b = src[fphys(v + 1024)];
            float2 c = src[fphys(v + 2048)];
            float2 d = src[fphys(v + 3072)];
            const int i1 = p << sh;
            float2 w1 = tw4[i1];
            float2 w2 = tw4[2 * i1];
            float2 w3 = tw4[3 * i1];
            float apcx = a.x + c.x, apcy = a.y + c.y;
            float amcx = a.x - c.x, amcy = a.y - c.y;
            float bpdx = b.x + d.x, bpdy = b.y + d.y;
            float sjx = -syf * (b.y - d.y);
            float sjy =  syf * (b.x - d.x);
            float2 x0 = make_float2(apcx + bpdx, apcy + bpdy);
            float t1x = amcx - sjx, t1y = amcy - sjy;
            float t2x = apcx - bpdx, t2y = apcy - bpdy;
            float t3x = amcx + sjx, t3y = amcy + sjy;
            float cs1 = w1.x, sn1 = syf * w1.y;
            float cs2 = w2.x, sn2 = syf * w2.y;
            float cs3 = w3.x, sn3 = syf * w3.y;
            float2 x1 = make_float2(cs1 * t1x - sn1 * t1y, cs1 * t1y + sn1 * t1x);
            float2 x2 = make_float2(cs2 * t2x - sn2 * t2y, cs2 * t2y + sn2 * t2x);
            float2 x3 = make_float2(cs3 * t3x - sn3 * t3y, cs3 * t3y + sn3 * t3x);
            const int ob = q + (p << (sh + 2));
            dst[fphys(ob)]         = x0;
            dst[fphys(ob + s)]     = x1;
            dst[fphys(ob + 2 * s)] = x2;
            dst[fphys(ob + 3 * s)] = x3;
        }
        __syncthreads();
        float2* tmp = src; src = dst; dst = tmp;
    }
    return src;
}

__global__ __launch_bounds__(512) void fft_fwd_packed(const float* __restrict__ x,
                                                      const float2* __restrict__ tw4,
                                                      float2* __restrict__ Xs)
{
    int rp = blockIdx.x;
    int b = rp / 6, c0 = (rp % 6) * 2;
    __shared__ float2 bufA[T_LEN];
    __shared__ float2 bufB[T_LEN];
    for (int t = threadIdx.x; t < T_LEN; t += 512) {
        const float* px = x + ((size_t)b * T_LEN + t) * C_IN + c0;
        bufA[fphys(t)] = make_float2(px[0], px[1]);
    }
    __syncthreads();
    float2* Z = fft_stages4(bufA, bufB, tw4, 1.f);
    size_t row = (size_t)b * C_IN + c0;
    for (int f = threadIdx.x; f <= 2048; f += 512) {
        float2 z  = Z[fphys(f)];
        float2 zm = Z[fphys((T_LEN - f) & (T_LEN - 1))];
        Xs[row * NBINS + f]       = make_float2(0.5f * (z.x + zm.x), 0.5f * (z.y - zm.y));
        Xs[(row + 1) * NBINS + f] = make_float2(0.5f * (z.y + zm.y), 0.5f * (zm.x - z.x));
    }
}

__global__ __launch_bounds__(512) void fft_inv_packed(const float2* __restrict__ Xs,
                                                      const float* __restrict__ g,
                                                      const float2* __restrict__ tw4,
                                                      unsigned int* __restrict__ modeU)
{
    int rp = blockIdx.x;
    int kk = blockIdx.y;
    int b = rp / 6, pr = rp % 6;
    int c0 = pr * 2;
    size_t rowa = (size_t)b * C_IN + c0;
    __shared__ float2 bufA[T_LEN];
    __shared__ float2 bufB[T_LEN];
    const float* gk = g + kk * NBINS;
    for (int f = threadIdx.x; f < T_LEN; f += 512) {
        int fe = (f <= 2048) ? f : (T_LEN - f);
        float2 A  = Xs[rowa * NBINS + fe];
        float2 Bv = Xs[(rowa + 1) * NBINS + fe];
        float gv = gk[fe];
        if (f > 2048) { A.y = -A.y; Bv.y = -Bv.y; }
        bufA[fphys(f)] = make_float2(gv * (A.x - Bv.y), gv * (A.y + Bv.x));
    }
    __syncthreads();
    float2* z = fft_stages4(bufA, bufB, tw4, -1.f);
    const float invn = 1.f / (float)T_LEN;
    unsigned int* plane = modeU + (((size_t)kk * B_SZ + b) * 6 + pr) * T_LEN;
    for (int t = threadIdx.x; t < T_LEN; t += 512) {
        float2 zz = z[fphys(t)];
        unsigned int pk = (unsigned int)f2bf(zz.x * invn) |
                          ((unsigned int)f2bf(zz.y * invn) << 16);
        plane[t] = pk;
    }
}

// ---------------------------------------------------------------------------
// Fused conv1+conv2+conv3, 256-t tiles, 512 threads (8 waves). All index
// formulas identical to the r20-verified 128-t version (parametric in
// absolute t; swizzle keys use global superrow parity; t0 mult of 8).
// LDS: h2l 272rows*128B @0..34816 (overlaps Xl1 9472B, dead by then);
//      h1l 144sr*128B  @34816..53248.
// ---------------------------------------------------------------------------
__global__ __launch_bounds__(512) void fused_conv(
    const unsigned int* __restrict__ modeU,      // [k][b][pair][t] uints
    const unsigned short* __restrict__ Wp1all,
    const unsigned short* __restrict__ Wp2all,
    const unsigned short* __restrict__ Wp3all,
    const float* __restrict__ b1, const float* __restrict__ g1, const float* __restrict__ be1,
    const float* __restrict__ b2, const float* __restrict__ g2, const float* __restrict__ be2,
    const float* __restrict__ b3, const float* __restrict__ g3, const float* __restrict__ be3,
    float* __restrict__ feats)
{
    __shared__ __align__(16) char smem[53248];
    char* Xl1 = smem;               // 9472 B (74 superrows)
    char* h2l = smem;               // 34816 B (overlaps Xl1; Xl1 dead by then)
    char* h1l = smem + 34816;       // 18432 B (144 superrows)

    const int b  = blockIdx.y;
    const int kk = blockIdx.z;
    const int t0 = blockIdx.x * 256;
    const int tid = threadIdx.x;
    const int sr0 = t0 >> 2;

    const unsigned int* planes = modeU + ((size_t)kk * B_SZ + b) * 6 * T_LEN;
    const unsigned short* Wp1 = Wp1all + (size_t)kk * 4096;
    const unsigned short* Wp2 = Wp2all + (size_t)kk * 5 * 2048;
    const unsigned short* Wp3 = Wp3all + (size_t)kk * 3 * 64 * 64;

    const float rs = 1.f / sqrtf(1.f + 1e-5f);
    const int w  = tid >> 6;
    const int l  = tid & 63;
    const int lo = l & 15;
    const int hi = l >> 4;

    // ---- stage mode: 8 pair-slots x 74 superrows (t in [t0-20, t0+275]) ----
    for (int i = tid; i < 592; i += 512) {
        int p = i / 74;
        int ls = i % 74;
        int sr_g = sr0 - 5 + ls;
        int t_base = sr_g * 4;
        unsigned int vv[4] = {0u, 0u, 0u, 0u};
        if (p < 6) {
            const unsigned int* pl = planes + (size_t)p * T_LEN;
            if (t_base >= 0 && t_base + 3 < T_LEN) {
                uint4 v4 = *(const uint4*)(pl + t_base);
                vv[0] = v4.x; vv[1] = v4.y; vv[2] = v4.z; vv[3] = v4.w;
            } else {
#pragma unroll
                for (int e = 0; e < 4; ++e) {
                    int t = t_base + e;
                    vv[e] = (t >= 0 && t < T_LEN) ? pl[t] : 0u;
                }
            }
        }
        int cb = p >> 2, j = p & 3;
        int key = sr_g & 7;
#pragma unroll
        for (int e = 0; e < 4; ++e) {
            int q = e * 2 + cb;
            int qp = q ^ key;
            *(unsigned int*)(Xl1 + (size_t)ls * 128 + qp * 16 + j * 4) = vv[e];
        }
    }

    // conv1 B-fragments (global, L1-resident)
    short8v Bf1[4][2];
#pragma unroll
    for (int dp = 0; dp < 4; ++dp)
#pragma unroll
        for (int n = 0; n < 2; ++n) {
            int o = n * 16 + lo;
            Bf1[dp][n] = *(const short8v*)((const char*)Wp1 + dp * 2048 + o * 64 + hi * 16);
        }
    __syncthreads();

    // ---- conv1: outputs t in [t0-16, t0+272), 18 m-tiles ----
    for (int mt = w; mt < 18; mt += 8) {
        int tbase = t0 - 16 + mt * 16;
        floatx4 a1[2];
        a1[0] = (floatx4){0.f, 0.f, 0.f, 0.f};
        a1[1] = (floatx4){0.f, 0.f, 0.f, 0.f};
#pragma unroll
        for (int dp = 0; dp < 4; ++dp) {
            int t_in = tbase + lo + dp * 2 + (hi >> 1) - 3;
            int sr_g = t_in >> 2;
            int ls = sr_g - sr0 + 5;
            int q = (t_in & 3) * 2 + (hi & 1);
            int qp = q ^ (sr_g & 7);
            short8v Af = *(const short8v*)(Xl1 + (size_t)ls * 128 + qp * 16);
#pragma unroll
            for (int n = 0; n < 2; ++n)
                a1[n] = __builtin_amdgcn_mfma_f32_16x16x32_bf16(Af, Bf1[dp][n], a1[n], 0, 0, 0);
        }
#pragma unroll
        for (int n = 0; n < 2; ++n) {
            int o = n * 16 + lo;
            float sc = g1[kk * 32 + o] * rs;
            float bb = fmaf(b1[kk * 32 + o], sc, be1[kk * 32 + o]);
#pragma unroll
            for (int r = 0; r < 4; ++r) {
                int tl1 = mt * 16 + 4 * hi + r;
                int tg = t0 - 16 + tl1;
                float v = (tg >= 0 && tg < T_LEN)
                              ? fmaxf(fmaf(a1[n][r], sc, bb), 0.f) : 0.f;
                int s1 = tl1 >> 1;
                int q = (tl1 & 1) * 4 + (o >> 3);
                int qp = q ^ (s1 & 7);
                *(unsigned short*)(h1l + (size_t)s1 * 128 + qp * 16 + (o & 7) * 2) = f2bf(v);
            }
        }
    }

    // conv2 B-fragments
    short8v Bf2[5][4];
#pragma unroll
    for (int d = 0; d < 5; ++d)
#pragma unroll
        for (int n = 0; n < 4; ++n) {
            int o = n * 16 + lo;
            int sr = o >> 1;
            int q = (o & 1) * 4 + hi;
            int qp = q ^ (sr & 7);
            Bf2[d][n] = *(const short8v*)((const char*)Wp2 + (size_t)d * 4096 + sr * 128 + qp * 16);
        }
    __syncthreads();   // Xl1 dead; h1l complete

    // ---- conv2: outputs t in [t0-8, t0+264), 17 m-tiles, write h2l ----
    for (int mt2 = w; mt2 < 17; mt2 += 8) {
        floatx4 a2[4];
#pragma unroll
        for (int n = 0; n < 4; ++n) a2[n] = (floatx4){0.f, 0.f, 0.f, 0.f};
#pragma unroll
        for (int d = 0; d < 5; ++d) {
            int tl_f = mt2 * 16 + lo + d + 6;       // input row in h1l
            int s = tl_f >> 1;
            int q = (tl_f & 1) * 4 + hi;
            int qp = q ^ (s & 7);
            short8v Af = *(const short8v*)(h1l + (size_t)s * 128 + qp * 16);
#pragma unroll
            for (int n = 0; n < 4; ++n)
                a2[n] = __builtin_amdgcn_mfma_f32_16x16x32_bf16(Af, Bf2[d][n], a2[n], 0, 0, 0);
        }
#pragma unroll
        for (int n = 0; n < 4; ++n) {
            int o = n * 16 + lo;
            float sc = g2[kk * 64 + o] * rs;
            float bb = fmaf(b2[kk * 64 + o], sc, be2[kk * 64 + o]);
            int cq = o >> 3;
#pragma unroll
            for (int r = 0; r < 4; ++r) {
                int tl2 = mt2 * 16 + 4 * hi + r;
                int tg = t0 - 8 + tl2;
                float v = (tg >= 0 && tg < T_LEN)
                              ? fmaxf(fmaf(a2[n][r], sc, bb), 0.f) : 0.f;
                int blk = cq ^ (tl2 & 7);
                *(unsigned short*)(h2l + (size_t)tl2 * 128 + blk * 16 + (o & 7) * 2) = f2bf(v);
            }
        }
    }

    // conv3 B-fragments
    short8v Bf3[6][4];
#pragma unroll
    for (int d = 0; d < 3; ++d)
#pragma unroll
        for (int ch = 0; ch < 2; ++ch)
#pragma unroll
            for (int n = 0; n < 4; ++n) {
                int o = n * 16 + lo;
                int blk = (4 * ch + hi) ^ (o & 7);
                Bf3[d * 2 + ch][n] =
                    *(const short8v*)((const char*)Wp3 + (size_t)(d * 64 + o) * 128 + blk * 16);
            }
    __syncthreads();   // h2l complete

    // ---- conv3 + mean: outputs t in [t0, t0+256), wave w owns 32 t ----
    floatx4 acc[2][4];
#pragma unroll
    for (int m = 0; m < 2; ++m)
#pragma unroll
        for (int n = 0; n < 4; ++n)
            acc[m][n] = (floatx4){0.f, 0.f, 0.f, 0.f};

#pragma unroll
    for (int d = 0; d < 3; ++d)
#pragma unroll
        for (int ch = 0; ch < 2; ++ch) {
#pragma unroll
            for (int m = 0; m < 2; ++m) {
                int tl = w * 32 + m * 16 + lo + d;     // row 0 = t0-1
                int row = tl + 7;                      // h2l base is t0-8
                int blk = (4 * ch + hi) ^ ((tl - 1) & 7);
                short8v Af = *(const short8v*)(h2l + (size_t)row * 128 + blk * 16);
#pragma unroll
                for (int n = 0; n < 4; ++n)
                    acc[m][n] = __builtin_amdgcn_mfma_f32_16x16x32_bf16(
                        Af, Bf3[d * 2 + ch][n], acc[m][n], 0, 0, 0);
            }
        }

#pragma unroll
    for (int n = 0; n < 4; ++n) {
        int o = n * 16 + lo;
        float sc = g3[kk * 64 + o] * rs;
        float bb = fmaf(b3[kk * 64 + o], sc, be3[kk * 64 + o]);
        float s = 0.f;
#pragma unroll
        for (int m = 0; m < 2; ++m)
#pragma unroll
            for (int r = 0; r < 4; ++r)
                s += fmaxf(fmaf(acc[m][n][r], sc, bb), 0.f);
        s += __shfl_xor(s, 16, 64);
        s += __shfl_xor(s, 32, 64);
        if (hi == 0)
            atomicAdd(&feats[b * (KM * FEAT) + kk * FEAT + o], s * (1.f / (float)T_LEN));
    }
}

// ---------------------------------------------------------------------------
// Classifier
// ---------------------------------------------------------------------------
__global__ __launch_bounds__(128) void classifier_kernel(const float* __restrict__ feats,
                                                         const float* __restrict__ Wc1,
                                                         const float* __restrict__ bc1,
                                                         const float* __restrict__ Wc2,
                                                         const float* __restrict__ bc2,
                                                         float* __restrict__ out)
{
    int b = blockIdx.x;
    int j = threadIdx.x;
    __shared__ float h[128];
    float acc = bc1[j];
    const float* fb = feats + b * 256;
    for (int i = 0; i < 256; ++i) acc = fmaf(fb[i], Wc1[j * 256 + i], acc);
    h[j] = fmaxf(acc, 0.f);
    __syncthreads();
    if (j < 10) {
        float acc2 = bc2[j];
        for (int i = 0; i < 128; ++i) acc2 = fmaf(h[i], Wc2[j * 128 + i], acc2);
        out[b * 10 + j] = acc2;
    }
}

extern "C" void kernel_launch(void* const* d_in, const int* in_sizes, int n_in,
                              void* d_out, int out_size, void* d_ws, size_t ws_size,
                              hipStream_t stream)
{
    const float* x     = (const float*)d_in[0];
    const float* alpha = (const float*)d_in[1];
    const float* tau   = (const float*)d_in[2];
    const float* omega = (const float*)d_in[3];
    const float* W1    = (const float*)d_in[4];
    const float* b1    = (const float*)d_in[5];
    const float* g1    = (const float*)d_in[6];
    const float* be1   = (const float*)d_in[7];
    const float* W2    = (const float*)d_in[8];
    const float* b2    = (const float*)d_in[9];
    const float* g2    = (const float*)d_in[10];
    const float* be2   = (const float*)d_in[11];
    const float* W3    = (const float*)d_in[12];
    const float* b3    = (const float*)d_in[13];
    const float* g3    = (const float*)d_in[14];
    const float* be3   = (const float*)d_in[15];
    const float* Wc1   = (const float*)d_in[16];
    const float* bc1   = (const float*)d_in[17];
    const float* Wc2   = (const float*)d_in[18];
    const float* bc2   = (const float*)d_in[19];

    const int NROWS = B_SZ * C_IN;   // 768
    float* ws = (float*)d_ws;
    float2* tw4  = (float2*)ws;                                  // 8192 floats
    float* g     = ws + 8192;                                    // 8196 floats
    float2* Xs   = (float2*)(ws + 8192 + 4 * NBINS);             // 12.6 MB
    unsigned int* modeU = (unsigned int*)(ws + 8192 + 4 * NBINS + (size_t)NROWS * NBINS * 2);
    // modeU: 25.2 MB
    float* feats = (float*)(modeU + (size_t)KM * B_SZ * 6 * T_LEN);
    unsigned short* Wp1 = (unsigned short*)(feats + B_SZ * KM * FEAT);
    unsigned short* Wp2 = Wp1 + KM * 4096;
    unsigned short* Wp3 = Wp2 + KM * 5 * 2048;

    const int PREP_TOT = 4096 + NBINS + B_SZ * KM * FEAT +
                         KM * 4 * 32 * 32 + KM * 5 * 64 * 32 + KM * 3 * 64 * 64;
    prep_all<<<(PREP_TOT + 255) / 256, 256, 0, stream>>>(
        alpha, tau, omega, W1, W2, W3, tw4, g, feats, Wp1, Wp2, Wp3);

    fft_fwd_packed<<<NROWS / 2, 512, 0, stream>>>(x, tw4, Xs);
    fft_inv_packed<<<dim3(NROWS / 2, KM), 512, 0, stream>>>(Xs, g, tw4, modeU);

    fused_conv<<<dim3(T_LEN / 256, B_SZ, KM), 512, 0, stream>>>(
        modeU, Wp1, Wp2, Wp3,
        b1, g1, be1, b2, g2, be2, b3, g3, be3, feats);

    classifier_kernel<<<B_SZ, 128, 0, stream>>>(feats, Wc1, bc1, Wc2, bc2, (float*)d_out);
}

// Round 24
// 186.064 us; speedup vs baseline: 1.2451x; 1.2451x over previous
//
#include <hip/hip_runtime.h>
#include <math.h>

#define T_LEN 4096
#define NBINS 2049          // T/2+1
#define B_SZ 64
#define C_IN 12
#define KM 4
#define FEAT 64

typedef __attribute__((ext_vector_type(8))) short short8v;   // 8 bf16 (4 VGPRs)
typedef __attribute__((ext_vector_type(4))) float floatx4;

// fp32 -> bf16 with RNE
__device__ __forceinline__ unsigned short f2bf(float f)
{
    unsigned int u = __float_as_uint(f);
    u += 0x7FFFu + ((u >> 16) & 1u);
    return (unsigned short)(u >> 16);
}

// FFT LDS swizzle (complex-index involution)
__device__ __forceinline__ int fphys(int i) { return i ^ ((i >> 4) & 15); }

// ---------------------------------------------------------------------------
// prep_all: twiddles (4096), gains (2049), feats-zero, 3 weight repacks.
// ---------------------------------------------------------------------------
__global__ void prep_all(const float* __restrict__ alpha,
                         const float* __restrict__ tau,
                         const float* __restrict__ omega,
                         const float* __restrict__ W1,
                         const float* __restrict__ W2,
                         const float* __restrict__ W3,
                         float2* __restrict__ tw4,
                         float* __restrict__ g,
                         float* __restrict__ feats,
                         unsigned short* __restrict__ Wp1,
                         unsigned short* __restrict__ Wp2,
                         unsigned short* __restrict__ Wp3)
{
    int gid = blockIdx.x * 256 + threadIdx.x;
    if (gid < 4096) {
        float ang = -(float)M_PI * (float)gid / 2048.0f;
        float sn, cs;
        sincosf(ang, &sn, &cs);
        tw4[gid] = make_float2(cs, sn);
        return;
    }
    gid -= 4096;
    if (gid < NBINS) {
        int f = gid;
        float freq = 0.5f * (float)f / 2048.0f;
        float a[4] = {0.f, 0.f, 0.f, 0.f};
        float s = 0.f, lamc = 0.f;
        for (int l = 0; l < 8; ++l) {
            for (int k = 0; k < 4; ++k) {
                float r = 1.f - (s - a[k]) + 0.5f * lamc;
                float d = freq - omega[k];
                float denom = 1.f + alpha[l * 4 + k] * d * d;
                float anew = r / denom;
                s += anew - a[k];
                a[k] = anew;
            }
            lamc += tau[l] * (1.f - s);
        }
        for (int k = 0; k < 4; ++k) g[k * NBINS + f] = a[k];
        return;
    }
    gid -= NBINS;
    if (gid < B_SZ * KM * FEAT) { feats[gid] = 0.f; return; }
    gid -= B_SZ * KM * FEAT;
    if (gid < KM * 4 * 32 * 32) {
        int i = gid;
        int kidx  = i & 31;
        int o     = (i >> 5) & 31;
        int dpair = (i >> 10) & 3;
        int k     = i >> 12;
        int d = dpair * 2 + (kidx >> 4);
        int c = kidx & 15;
        float v = (d < 7 && c < 12) ? W1[(((size_t)k * 32 + o) * 12 + c) * 7 + d] : 0.f;
        Wp1[(size_t)k * 4096 + dpair * 1024 + o * 32 + kidx] = f2bf(v);
        return;
    }
    gid -= KM * 4 * 32 * 32;
    if (gid < KM * 5 * 64 * 32) {
        int i = gid;
        int c = i & 31;
        int o = (i >> 5) & 63;
        int kd = i >> 11;
        int d = kd % 5, k = kd / 5;
        float v = W2[(((size_t)k * 64 + o) * 32 + c) * 5 + d];
        int sr = o >> 1;
        int q = (o & 1) * 4 + (c >> 3);
        int qp = q ^ (sr & 7);
        Wp2[(size_t)(k * 5 + d) * 2048 + sr * 64 + qp * 8 + (c & 7)] = f2bf(v);
        return;
    }
    gid -= KM * 5 * 64 * 32;
    if (gid < KM * 3 * 64 * 64) {
        int i = gid;
        int c = i & 63;
        int o = (i >> 6) & 63;
        int kd = i >> 12;
        int d = kd % 3, k = kd / 3;
        float v = W3[(((size_t)k * 64 + o) * 64 + c) * 3 + d];
        int blk = (c >> 3) ^ (o & 7);
        Wp3[(size_t)k * (3 * 64 * 64) + (d * 64 + o) * 64 + blk * 8 + (c & 7)] = f2bf(v);
        return;
    }
}

// ---------------------------------------------------------------------------
// Radix-4 Stockham, N=4096, 6 stages, swizzled LDS (verified r16).
// ---------------------------------------------------------------------------
__device__ inline float2* fft_stages4(float2* bufA, float2* bufB,
                                      const float2* __restrict__ tw4, float syf)
{
    float2* src = bufA;
    float2* dst = bufB;
#pragma unroll
    for (int st = 0; st < 6; ++st) {
        const int sh = 2 * st;
        const int s = 1 << sh;
        for (int v = threadIdx.x; v < 1024; v += 512) {
            const int q = v & (s - 1);
            const int p = v >> sh;
            float2 a = src[fphys(v)];
            float2 b = src[fphys(v + 1024)];
            float2 c = src[fphys(v + 2048)];
            float2 d = src[fphys(v + 3072)];
            const int i1 = p << sh;
            float2 w1 = tw4[i1];
            float2 w2 = tw4[2 * i1];
            float2 w3 = tw4[3 * i1];
            float apcx = a.x + c.x, apcy = a.y + c.y;
            float amcx = a.x - c.x, amcy = a.y - c.y;
            float bpdx = b.x + d.x, bpdy = b.y + d.y;
            float sjx = -syf * (b.y - d.y);
            float sjy =  syf * (b.x - d.x);
            float2 x0 = make_float2(apcx + bpdx, apcy + bpdy);
            float t1x = amcx - sjx, t1y = amcy - sjy;
            float t2x = apcx - bpdx, t2y = apcy - bpdy;
            float t3x = amcx + sjx, t3y = amcy + sjy;
            float cs1 = w1.x, sn1 = syf * w1.y;
            float cs2 = w2.x, sn2 = syf * w2.y;
            float cs3 = w3.x, sn3 = syf * w3.y;
            float2 x1 = make_float2(cs1 * t1x - sn1 * t1y, cs1 * t1y + sn1 * t1x);
            float2 x2 = make_float2(cs2 * t2x - sn2 * t2y, cs2 * t2y + sn2 * t2x);
            float2 x3 = make_float2(cs3 * t3x - sn3 * t3y, cs3 * t3y + sn3 * t3x);
            const int ob = q + (p << (sh + 2));
            dst[fphys(ob)]         = x0;
            dst[fphys(ob + s)]     = x1;
            dst[fphys(ob + 2 * s)] = x2;
            dst[fphys(ob + 3 * s)] = x3;
        }
        __syncthreads();
        float2* tmp = src; src = dst; dst = tmp;
    }
    return src;
}

__global__ __launch_bounds__(512) void fft_fwd_packed(const float* __restrict__ x,
                                                      const float2* __restrict__ tw4,
                                                      float2* __restrict__ Xs)
{
    int rp = blockIdx.x;
    int b = rp / 6, c0 = (rp % 6) * 2;
    __shared__ float2 bufA[T_LEN];
    __shared__ float2 bufB[T_LEN];
    for (int t = threadIdx.x; t < T_LEN; t += 512) {
        const float* px = x + ((size_t)b * T_LEN + t) * C_IN + c0;
        bufA[fphys(t)] = make_float2(px[0], px[1]);
    }
    __syncthreads();
    float2* Z = fft_stages4(bufA, bufB, tw4, 1.f);
    size_t row = (size_t)b * C_IN + c0;
    for (int f = threadIdx.x; f <= 2048; f += 512) {
        float2 z  = Z[fphys(f)];
        float2 zm = Z[fphys((T_LEN - f) & (T_LEN - 1))];
        Xs[row * NBINS + f]       = make_float2(0.5f * (z.x + zm.x), 0.5f * (z.y - zm.y));
        Xs[(row + 1) * NBINS + f] = make_float2(0.5f * (z.y + zm.y), 0.5f * (zm.x - z.x));
    }
}

__global__ __launch_bounds__(512) void fft_inv_packed(const float2* __restrict__ Xs,
                                                      const float* __restrict__ g,
                                                      const float2* __restrict__ tw4,
                                                      unsigned int* __restrict__ modeU)
{
    int rp = blockIdx.x;
    int kk = blockIdx.y;
    int b = rp / 6, pr = rp % 6;
    int c0 = pr * 2;
    size_t rowa = (size_t)b * C_IN + c0;
    __shared__ float2 bufA[T_LEN];
    __shared__ float2 bufB[T_LEN];
    const float* gk = g + kk * NBINS;
    for (int f = threadIdx.x; f < T_LEN; f += 512) {
        int fe = (f <= 2048) ? f : (T_LEN - f);
        float2 A  = Xs[rowa * NBINS + fe];
        float2 Bv = Xs[(rowa + 1) * NBINS + fe];
        float gv = gk[fe];
        if (f > 2048) { A.y = -A.y; Bv.y = -Bv.y; }
        bufA[fphys(f)] = make_float2(gv * (A.x - Bv.y), gv * (A.y + Bv.x));
    }
    __syncthreads();
    float2* z = fft_stages4(bufA, bufB, tw4, -1.f);
    const float invn = 1.f / (float)T_LEN;
    unsigned int* plane = modeU + (((size_t)kk * B_SZ + b) * 6 + pr) * T_LEN;
    for (int t = threadIdx.x; t < T_LEN; t += 512) {
        float2 zz = z[fphys(t)];
        unsigned int pk = (unsigned int)f2bf(zz.x * invn) |
                          ((unsigned int)f2bf(zz.y * invn) << 16);
        plane[t] = pk;
    }
}

// ---------------------------------------------------------------------------
// Fused conv1+conv2+conv3 (r20-verified configuration: 128-t tile, 4 waves,
// measured 130us kernel / 186us total, twice reproduced). All intermediates
// in LDS; edge blocks zero outputs for t outside [0,T).
// ---------------------------------------------------------------------------
__global__ __launch_bounds__(256) void fused_conv(
    const unsigned int* __restrict__ modeU,      // [k][b][pair][t] uints
    const unsigned short* __restrict__ Wp1all,
    const unsigned short* __restrict__ Wp2all,
    const unsigned short* __restrict__ Wp3all,
    const float* __restrict__ b1, const float* __restrict__ g1, const float* __restrict__ be1,
    const float* __restrict__ b2, const float* __restrict__ g2, const float* __restrict__ be2,
    const float* __restrict__ b3, const float* __restrict__ g3, const float* __restrict__ be3,
    float* __restrict__ feats)
{
    __shared__ __align__(16) char smem[28672];
    char* Xl1 = smem;               // 5376 B
    char* h2l = smem;               // 18432 B (overlaps Xl1; Xl1 dead by then)
    char* h1l = smem + 18432;       // 10240 B

    const int b  = blockIdx.y;
    const int kk = blockIdx.z;
    const int t0 = blockIdx.x * 128;
    const int tid = threadIdx.x;
    const int sr0 = t0 >> 2;

    const unsigned int* planes = modeU + ((size_t)kk * B_SZ + b) * 6 * T_LEN;
    const unsigned short* Wp1 = Wp1all + (size_t)kk * 4096;
    const unsigned short* Wp2 = Wp2all + (size_t)kk * 5 * 2048;
    const unsigned short* Wp3 = Wp3all + (size_t)kk * 3 * 64 * 64;

    const float rs = 1.f / sqrtf(1.f + 1e-5f);
    const int w  = tid >> 6;
    const int l  = tid & 63;
    const int lo = l & 15;
    const int hi = l >> 4;

    // ---- stage mode: 8 pair-slots x 42 superrows (t in [t0-20, t0+147]) ----
    for (int i = tid; i < 336; i += 256) {
        int p = i / 42;
        int ls = i % 42;
        int sr_g = sr0 - 5 + ls;
        int t_base = sr_g * 4;
        unsigned int vv[4] = {0u, 0u, 0u, 0u};
        if (p < 6) {
            const unsigned int* pl = planes + (size_t)p * T_LEN;
            if (t_base >= 0 && t_base + 3 < T_LEN) {
                uint4 v4 = *(const uint4*)(pl + t_base);
                vv[0] = v4.x; vv[1] = v4.y; vv[2] = v4.z; vv[3] = v4.w;
            } else {
#pragma unroll
                for (int e = 0; e < 4; ++e) {
                    int t = t_base + e;
                    vv[e] = (t >= 0 && t < T_LEN) ? pl[t] : 0u;
                }
            }
        }
        int cb = p >> 2, j = p & 3;
        int key = sr_g & 7;
#pragma unroll
        for (int e = 0; e < 4; ++e) {
            int q = e * 2 + cb;
            int qp = q ^ key;
            *(unsigned int*)(Xl1 + (size_t)ls * 128 + qp * 16 + j * 4) = vv[e];
        }
    }

    // conv1 B-fragments (global, L1-resident)
    short8v Bf1[4][2];
#pragma unroll
    for (int dp = 0; dp < 4; ++dp)
#pragma unroll
        for (int n = 0; n < 2; ++n) {
            int o = n * 16 + lo;
            Bf1[dp][n] = *(const short8v*)((const char*)Wp1 + dp * 2048 + o * 64 + hi * 16);
        }
    __syncthreads();

    // ---- conv1: outputs t in [t0-16, t0+144), 10 m-tiles, per-tile write ----
    for (int mt = w; mt < 10; mt += 4) {
        int tbase = t0 - 16 + mt * 16;
        floatx4 a1[2];
        a1[0] = (floatx4){0.f, 0.f, 0.f, 0.f};
        a1[1] = (floatx4){0.f, 0.f, 0.f, 0.f};
#pragma unroll
        for (int dp = 0; dp < 4; ++dp) {
            int t_in = tbase + lo + dp * 2 + (hi >> 1) - 3;
            int sr_g = t_in >> 2;
            int ls = sr_g - sr0 + 5;
            int q = (t_in & 3) * 2 + (hi & 1);
            int qp = q ^ (sr_g & 7);
            short8v Af = *(const short8v*)(Xl1 + (size_t)ls * 128 + qp * 16);
#pragma unroll
            for (int n = 0; n < 2; ++n)
                a1[n] = __builtin_amdgcn_mfma_f32_16x16x32_bf16(Af, Bf1[dp][n], a1[n], 0, 0, 0);
        }
#pragma unroll
        for (int n = 0; n < 2; ++n) {
            int o = n * 16 + lo;
            float sc = g1[kk * 32 + o] * rs;
            float bb = fmaf(b1[kk * 32 + o], sc, be1[kk * 32 + o]);
#pragma unroll
            for (int r = 0; r < 4; ++r) {
                int tl1 = mt * 16 + 4 * hi + r;
                int tg = t0 - 16 + tl1;
                float v = (tg >= 0 && tg < T_LEN)
                              ? fmaxf(fmaf(a1[n][r], sc, bb), 0.f) : 0.f;
                int s1 = tl1 >> 1;
                int q = (tl1 & 1) * 4 + (o >> 3);
                int qp = q ^ (s1 & 7);
                *(unsigned short*)(h1l + (size_t)s1 * 128 + qp * 16 + (o & 7) * 2) = f2bf(v);
            }
        }
    }

    // conv2 B-fragments
    short8v Bf2[5][4];
#pragma unroll
    for (int d = 0; d < 5; ++d)
#pragma unroll
        for (int n = 0; n < 4; ++n) {
            int o = n * 16 + lo;
            int sr = o >> 1;
            int q = (o & 1) * 4 + hi;
            int qp = q ^ (sr & 7);
            Bf2[d][n] = *(const short8v*)((const char*)Wp2 + (size_t)d * 4096 + sr * 128 + qp * 16);
        }
    __syncthreads();   // Xl1 dead; h1l complete

    // ---- conv2: outputs t in [t0-8, t0+136), 9 m-tiles, write h2l ----
    for (int mt2 = w; mt2 < 9; mt2 += 4) {
        floatx4 a2[4];
#pragma unroll
        for (int n = 0; n < 4; ++n) a2[n] = (floatx4){0.f, 0.f, 0.f, 0.f};
#pragma unroll
        for (int d = 0; d < 5; ++d) {
            int tl_f = mt2 * 16 + lo + d + 6;       // input row in h1l
            int s = tl_f >> 1;
            int q = (tl_f & 1) * 4 + hi;
            int qp = q ^ (s & 7);
            short8v Af = *(const short8v*)(h1l + (size_t)s * 128 + qp * 16);
#pragma unroll
            for (int n = 0; n < 4; ++n)
                a2[n] = __builtin_amdgcn_mfma_f32_16x16x32_bf16(Af, Bf2[d][n], a2[n], 0, 0, 0);
        }
#pragma unroll
        for (int n = 0; n < 4; ++n) {
            int o = n * 16 + lo;
            float sc = g2[kk * 64 + o] * rs;
            float bb = fmaf(b2[kk * 64 + o], sc, be2[kk * 64 + o]);
            int cq = o >> 3;
#pragma unroll
            for (int r = 0; r < 4; ++r) {
                int tl2 = mt2 * 16 + 4 * hi + r;
                int tg = t0 - 8 + tl2;
                float v = (tg >= 0 && tg < T_LEN)
                              ? fmaxf(fmaf(a2[n][r], sc, bb), 0.f) : 0.f;
                int blk = cq ^ (tl2 & 7);
                *(unsigned short*)(h2l + (size_t)tl2 * 128 + blk * 16 + (o & 7) * 2) = f2bf(v);
            }
        }
    }

    // conv3 B-fragments
    short8v Bf3[6][4];
#pragma unroll
    for (int d = 0; d < 3; ++d)
#pragma unroll
        for (int ch = 0; ch < 2; ++ch)
#pragma unroll
            for (int n = 0; n < 4; ++n) {
                int o = n * 16 + lo;
                int blk = (4 * ch + hi) ^ (o & 7);
                Bf3[d * 2 + ch][n] =
                    *(const short8v*)((const char*)Wp3 + (size_t)(d * 64 + o) * 128 + blk * 16);
            }
    __syncthreads();   // h2l complete

    // ---- conv3 + mean: outputs t in [t0, t0+128) ----
    floatx4 acc[2][4];
#pragma unroll
    for (int m = 0; m < 2; ++m)
#pragma unroll
        for (int n = 0; n < 4; ++n)
            acc[m][n] = (floatx4){0.f, 0.f, 0.f, 0.f};

#pragma unroll
    for (int d = 0; d < 3; ++d)
#pragma unroll
        for (int ch = 0; ch < 2; ++ch) {
#pragma unroll
            for (int m = 0; m < 2; ++m) {
                int tl = w * 32 + m * 16 + lo + d;     // row 0 = t0-1
                int row = tl + 7;                      // h2l base is t0-8
                int blk = (4 * ch + hi) ^ ((tl - 1) & 7);
                short8v Af = *(const short8v*)(h2l + (size_t)row * 128 + blk * 16);
#pragma unroll
                for (int n = 0; n < 4; ++n)
                    acc[m][n] = __builtin_amdgcn_mfma_f32_16x16x32_bf16(
                        Af, Bf3[d * 2 + ch][n], acc[m][n], 0, 0, 0);
            }
        }

#pragma unroll
    for (int n = 0; n < 4; ++n) {
        int o = n * 16 + lo;
        float sc = g3[kk * 64 + o] * rs;
        float bb = fmaf(b3[kk * 64 + o], sc, be3[kk * 64 + o]);
        float s = 0.f;
#pragma unroll
        for (int m = 0; m < 2; ++m)
#pragma unroll
            for (int r = 0; r < 4; ++r)
                s += fmaxf(fmaf(acc[m][n][r], sc, bb), 0.f);
        s += __shfl_xor(s, 16, 64);
        s += __shfl_xor(s, 32, 64);
        if (hi == 0)
            atomicAdd(&feats[b * (KM * FEAT) + kk * FEAT + o], s * (1.f / (float)T_LEN));
    }
}

// ---------------------------------------------------------------------------
// Classifier
// ---------------------------------------------------------------------------
__global__ __launch_bounds__(128) void classifier_kernel(const float* __restrict__ feats,
                                                         const float* __restrict__ Wc1,
                                                         const float* __restrict__ bc1,
                                                         const float* __restrict__ Wc2,
                                                         const float* __restrict__ bc2,
                                                         float* __restrict__ out)
{
    int b = blockIdx.x;
    int j = threadIdx.x;
    __shared__ float h[128];
    float acc = bc1[j];
    const float* fb = feats + b * 256;
    for (int i = 0; i < 256; ++i) acc = fmaf(fb[i], Wc1[j * 256 + i], acc);
    h[j] = fmaxf(acc, 0.f);
    __syncthreads();
    if (j < 10) {
        float acc2 = bc2[j];
        for (int i = 0; i < 128; ++i) acc2 = fmaf(h[i], Wc2[j * 128 + i], acc2);
        out[b * 10 + j] = acc2;
    }
}

extern "C" void kernel_launch(void* const* d_in, const int* in_sizes, int n_in,
                              void* d_out, int out_size, void* d_ws, size_t ws_size,
                              hipStream_t stream)
{
    const float* x     = (const float*)d_in[0];
    const float* alpha = (const float*)d_in[1];
    const float* tau   = (const float*)d_in[2];
    const float* omega = (const float*)d_in[3];
    const float* W1    = (const float*)d_in[4];
    const float* b1    = (const float*)d_in[5];
    const float* g1    = (const float*)d_in[6];
    const float* be1   = (const float*)d_in[7];
    const float* W2    = (const float*)d_in[8];
    const float* b2    = (const float*)d_in[9];
    const float* g2    = (const float*)d_in[10];
    const float* be2   = (const float*)d_in[11];
    const float* W3    = (const float*)d_in[12];
    const float* b3    = (const float*)d_in[13];
    const float* g3    = (const float*)d_in[14];
    const float* be3   = (const float*)d_in[15];
    const float* Wc1   = (const float*)d_in[16];
    const float* bc1   = (const float*)d_in[17];
    const float* Wc2   = (const float*)d_in[18];
    const float* bc2   = (const float*)d_in[19];

    const int NROWS = B_SZ * C_IN;   // 768
    float* ws = (float*)d_ws;
    float2* tw4  = (float2*)ws;                                  // 8192 floats
    float* g     = ws + 8192;                                    // 8196 floats
    float2* Xs   = (float2*)(ws + 8192 + 4 * NBINS);             // 12.6 MB
    unsigned int* modeU = (unsigned int*)(ws + 8192 + 4 * NBINS + (size_t)NROWS * NBINS * 2);
    // modeU: 25.2 MB
    float* feats = (float*)(modeU + (size_t)KM * B_SZ * 6 * T_LEN);
    unsigned short* Wp1 = (unsigned short*)(feats + B_SZ * KM * FEAT);
    unsigned short* Wp2 = Wp1 + KM * 4096;
    unsigned short* Wp3 = Wp2 + KM * 5 * 2048;

    const int PREP_TOT = 4096 + NBINS + B_SZ * KM * FEAT +
                         KM * 4 * 32 * 32 + KM * 5 * 64 * 32 + KM * 3 * 64 * 64;
    prep_all<<<(PREP_TOT + 255) / 256, 256, 0, stream>>>(
        alpha, tau, omega, W1, W2, W3, tw4, g, feats, Wp1, Wp2, Wp3);

    fft_fwd_packed<<<NROWS / 2, 512, 0, stream>>>(x, tw4, Xs);
    fft_inv_packed<<<dim3(NROWS / 2, KM), 512, 0, stream>>>(Xs, g, tw4, modeU);

    fused_conv<<<dim3(T_LEN / 128, B_SZ, KM), 256, 0, stream>>>(
        modeU, Wp1, Wp2, Wp3,
        b1, g1, be1, b2, g2, be2, b3, g3, be3, feats);

    classifier_kernel<<<B_SZ, 128, 0, stream>>>(feats, Wc1, bc1, Wc2, bc2, (float*)d_out);
}